// Round 4
// baseline (1409.675 us; speedup 1.0000x reference)
//
#include <hip/hip_runtime.h>
#include <math.h>

// ---- problem constants ----
#define BATCH   16
#define SEQ     4096
#define DMODEL  64
#define DINNER  128
#define DSTATE  32
#define NHEADS  2
#define HEADDIM 64
#define CONVDIM 192            // DINNER + 2*DSTATE
#define PROJ    322            // 2*DINNER + 2*DSTATE + NHEADS
#define QC      64             // chunk length for SSD scan
#define NCHUNK  (SEQ/QC)       // 64
#define BL      (BATCH*SEQ)    // 65536 rows
#define NPAD    336            // PROJ padded to 21*16 for MFMA col tiles

typedef __attribute__((ext_vector_type(8))) short short8;   // 8 bf16 (4 VGPRs)
typedef __attribute__((ext_vector_type(4))) float f32x4;    // MFMA C/D
typedef __attribute__((ext_vector_type(4))) unsigned short ushort4v;

__device__ inline unsigned short f2b(float f){
  union { float f; unsigned u; } v; v.f = f;
  unsigned r = v.u + 0x7FFF + ((v.u >> 16) & 1);   // round-to-nearest-even
  return (unsigned short)(r >> 16);
}
__device__ inline float b2f(unsigned short s){
  union { unsigned u; float f; } v; v.u = ((unsigned)s) << 16; return v.f;
}
// hi/lo split: x ~= hi + lo, residual ~2^-18 * x
__device__ inline void split2(float x, unsigned short& h, unsigned short& l){
  unsigned short hh = f2b(x);
  h = hh;
  l = f2b(x - b2f(hh));
}

// ---- static device scratch ----
// fp32 on the cross-kernel signal path (R5/R6 post-mortem: bf16 there fails).
__device__ float g_z   [(size_t)BL*DINNER];    // z (dense fp32)
__device__ float g_y   [(size_t)BL*DINNER];    // y_intra + D*x (fp32, exact fold)
__device__ unsigned short g_C[(size_t)BL*DSTATE]; // post-conv C (bf16)
__device__ float g_cum [BATCH*NHEADS*SEQ];
__device__ float g_ctot[BATCH*NHEADS*NCHUNK];
__device__ float g_S   [BATCH*NHEADS*NCHUNK*DSTATE*HEADDIM];
__device__ float g_H   [BATCH*NHEADS*NCHUNK*DSTATE*HEADDIM];
__device__ float g_ping0[(size_t)BL*DMODEL];
__device__ float g_ping1[(size_t)BL*DMODEL];
__device__ unsigned short g_WinTh [8*NPAD*DMODEL];
__device__ unsigned short g_WinTl [8*NPAD*DMODEL];
__device__ unsigned short g_WoutTh[8*DMODEL*DINNER];
__device__ unsigned short g_WoutTl[8*DMODEL*DINNER];

// ---- K0: prep transposed hi/lo bf16 weights ----
__global__ __launch_bounds__(256) void k_prep(const float* __restrict__ Win,
                                              const float* __restrict__ Wout,
                                              const float* __restrict__ normw) {
  const int idx = blockIdx.x*256 + threadIdx.x;
  const int NW = 8*NPAD*DMODEL;
  if (idx < NW) {
    int layer = idx / (NPAD*DMODEL);
    int rem   = idx - layer*(NPAD*DMODEL);
    int n = rem >> 6, k = rem & 63;
    float v = (n < PROJ) ? Win[(size_t)layer*DMODEL*PROJ + k*PROJ + n] : 0.f;
    split2(v, g_WinTh[idx], g_WinTl[idx]);
  } else {
    int i2 = idx - NW;
    if (i2 < 8*DMODEL*DINNER) {
      int layer = i2 / (DMODEL*DINNER);
      int rem   = i2 - layer*(DMODEL*DINNER);
      int n = rem >> 7, k = rem & 127;
      float v = Wout[(size_t)layer*DINNER*DMODEL + k*DMODEL + n] * normw[layer*DINNER + k];
      split2(v, g_WoutTh[i2], g_WoutTl[i2]);
    }
  }
}

// ---- K16 (fused inproj + chunkA), per (b,h,ch) block ----
// R16: wave-self-sufficient, 2 barriers (was 6).
//  - every wave redundantly computes the dt/cumsum scan (bit-identical);
//    cum/dt/ewl consumed via intra-wave __shfl (no LDS, no barrier).
//  - every wave recomputes its own 16-row halo tiles by MFMA with the same
//    fragment construction + op order as the producing wave -> bit-identical;
//    quad0's t-1..t-3 come from __shfl off the halo accumulator.
//  - z stored directly from MFMA-layout registers (no staging, no barrier).
//  - Gsh un-aliased from Bsh/Csh (no WAR barrier). LDS = 33,280 B -> 4 blocks/CU.
__global__ __launch_bounds__(256,4) void k_fusedAB(const float* __restrict__ xext, int sel,
                                                   const unsigned short* __restrict__ WinTh,
                                                   const unsigned short* __restrict__ WinTl,
                                                   const float* __restrict__ Win,
                                                   const float* __restrict__ dt_bias,
                                                   const float* __restrict__ A_log,
                                                   const float* __restrict__ conv_w,
                                                   const float* __restrict__ conv_b,
                                                   const float* __restrict__ Dp) {
  __shared__ struct {
    unsigned short Xt [64][72];        // X^T bf16 (9216 B)
    unsigned short Bt [32][72];        // (ew*B)^T bf16 (4608 B)
    unsigned short Bsh[64][40];        // 5120 B
    unsigned short Csh[64][40];        // 5120 B
    unsigned short Gsh[64][72];        // 9216 B
  } S_;                                // 33,280 B total

  const float* __restrict__ X = (sel==0) ? xext : (sel==1 ? g_ping0 : g_ping1);
  const int bx = blockIdx.x; const int b = bx>>7, h = (bx>>6)&1, ch = bx&63;
  const int tid = threadIdx.x;
  const int w = tid>>6, l = tid&63, lane15 = l&15, quad = l>>4;
  const size_t row0 = (size_t)b*SEQ + (size_t)ch*QC;
  const int cbase = (b*NHEADS+h)*SEQ + ch*QC;
  const float dph = Dp[h];

  // ---- main A fragments (rows row0+16w+lane15), in-register split ----
  const float* xrow = &X[(row0 + 16*w + lane15)*DMODEL + quad*8];
  float4 f0 = *(const float4*)(xrow);
  float4 f1 = *(const float4*)(xrow + 4);
  float4 f2 = *(const float4*)(xrow + 32);
  float4 f3 = *(const float4*)(xrow + 36);
  short8 a0h, a0l, a1h, a1l;
  {
    float v0[8] = {f0.x,f0.y,f0.z,f0.w,f1.x,f1.y,f1.z,f1.w};
    float v1[8] = {f2.x,f2.y,f2.z,f2.w,f3.x,f3.y,f3.z,f3.w};
    unsigned short hh, ll;
#pragma unroll
    for (int j=0;j<8;j++){ split2(v0[j], hh, ll); a0h[j]=(short)hh; a0l[j]=(short)ll; }
#pragma unroll
    for (int j=0;j<8;j++){ split2(v1[j], hh, ll); a1h[j]=(short)hh; a1l[j]=(short)ll; }
  }

  // ---- per-wave dt + cumsum scan (identical chain in every wave) ----
  float cum, dtv, ewl;
  {
    const int t = l;
    float acc = 0.f;
    const float* xr = &X[(row0+t)*DMODEL];
#pragma unroll
    for (int k=0;k<64;k++) acc = fmaf(xr[k], Win[k*PROJ + (DINNER+CONVDIM) + h], acc);
    float xv = acc + dt_bias[h];
    dtv = (xv > 20.f) ? xv : log1pf(expf(xv));
    float A = -expf(A_log[h]);
    cum = dtv * A;
#pragma unroll
    for (int off=1; off<64; off<<=1){
      float v = __shfl_up(cum, off);
      if (t >= off) cum += v;
    }
    if (w == 0){
      g_cum[cbase+t] = cum;
      if (t == 63) g_ctot[(b*NHEADS+h)*NCHUNK + ch] = cum;
    }
    float cl = __shfl(cum, 63);
    ewl = expf(cl - cum) * dtv;
  }

  // 6-MFMA split-precision tile (identical op order to R12/R15)
  auto MFMA6 = [&](short8 A0h, short8 A1h, short8 A0l, short8 A1l, int t)->f32x4 {
    const unsigned short* bph = &WinTh[(16*t + lane15)*64 + quad*8];
    const unsigned short* bpl = &WinTl[(16*t + lane15)*64 + quad*8];
    short8 b0h = *(const short8*)bph;
    short8 b1h = *(const short8*)(bph + 32);
    short8 b0l = *(const short8*)bpl;
    short8 b1l = *(const short8*)(bpl + 32);
    f32x4 acc = {0.f,0.f,0.f,0.f};
    acc = __builtin_amdgcn_mfma_f32_16x16x32_bf16(A0h, b0h, acc, 0, 0, 0);
    acc = __builtin_amdgcn_mfma_f32_16x16x32_bf16(A1h, b1h, acc, 0, 0, 0);
    acc = __builtin_amdgcn_mfma_f32_16x16x32_bf16(A0l, b0h, acc, 0, 0, 0);
    acc = __builtin_amdgcn_mfma_f32_16x16x32_bf16(A1l, b1h, acc, 0, 0, 0);
    acc = __builtin_amdgcn_mfma_f32_16x16x32_bf16(A0h, b0l, acc, 0, 0, 0);
    acc = __builtin_amdgcn_mfma_f32_16x16x32_bf16(A1h, b1l, acc, 0, 0, 0);
    return acc;
  };

  // ---- halo tiles: rows 16w-16..16w-1, recomputed by this wave itself ----
  const bool hvalid = (ch > 0) || (w > 0);
  f32x4 hA[4], hB[4];
  if (hvalid){
    const float* xh = &X[(row0 + 16*w - 16 + lane15)*DMODEL + quad*8];
    float4 g0 = *(const float4*)(xh);
    float4 g1 = *(const float4*)(xh + 4);
    float4 g2 = *(const float4*)(xh + 32);
    float4 g3 = *(const float4*)(xh + 36);
    short8 e0h, e0l, e1h, e1l;
    {
      float v0[8] = {g0.x,g0.y,g0.z,g0.w,g1.x,g1.y,g1.z,g1.w};
      float v1[8] = {g2.x,g2.y,g2.z,g2.w,g3.x,g3.y,g3.z,g3.w};
      unsigned short hh, ll;
#pragma unroll
      for (int j=0;j<8;j++){ split2(v0[j], hh, ll); e0h[j]=(short)hh; e0l[j]=(short)ll; }
#pragma unroll
      for (int j=0;j<8;j++){ split2(v1[j], hh, ll); e1h[j]=(short)hh; e1l[j]=(short)ll; }
    }
#pragma unroll
    for (int tt=0; tt<4; tt++) hA[tt] = MFMA6(e0h, e1h, e0l, e1l, 8+4*h+tt);
#pragma unroll
    for (int tt=0; tt<4; tt++) hB[tt] = MFMA6(e0h, e1h, e0l, e1l, 16+tt);
  } else {
    f32x4 zz = {0.f,0.f,0.f,0.f};
#pragma unroll
    for (int tt=0; tt<4; tt++){ hA[tt] = zz; hB[tt] = zz; }
  }

  // ---- z tiles first: direct stores from MFMA layout, frees registers ----
  {
#pragma unroll
    for (int tt=0; tt<4; tt++){
      f32x4 az = MFMA6(a0h, a1h, a0l, a1l, 4*h+tt);
#pragma unroll
      for (int r=0;r<4;r++)
        g_z[(row0 + 16*w + quad*4 + r)*DINNER + h*64 + tt*16 + lane15] = az[r];
    }
  }

  // ---- main pass tiles ----
  f32x4 pa[4];
#pragma unroll
  for (int tt=0; tt<4; tt++) pa[tt] = MFMA6(a0h, a1h, a0l, a1l, 8+4*h+tt);
  f32x4 pb[4];
#pragma unroll
  for (int tt=0; tt<4; tt++) pb[tt] = MFMA6(a0h, a1h, a0l, a1l, 16+tt);

  const int t0 = 16*w + quad*4;

  // ---- conv + silu for x channels (in-register; halo via shfl) ----
  float sv[4][4];    // silu(x) at (t0+r, 16tt+lane15) — feeds Xt AND the Y-fold
#pragma unroll
  for (int tt=0; tt<4; tt++){
    const int n = tt*16 + lane15;
    const int gch = h*64 + n;
    const float w0 = conv_w[gch*4+0], w1 = conv_w[gch*4+1], w2 = conv_w[gch*4+2], w3 = conv_w[gch*4+3];
    const float bb = conv_b[gch];
    float o0 = pa[tt][0], o1 = pa[tt][1], o2 = pa[tt][2], o3 = pa[tt][3];
    float p1 = __shfl_up(o3, 16), p2 = __shfl_up(o2, 16), p3 = __shfl_up(o1, 16);
    float q1 = __shfl(hA[tt][3], 48+lane15);
    float q2 = __shfl(hA[tt][2], 48+lane15);
    float q3 = __shfl(hA[tt][1], 48+lane15);
    if (quad == 0){ p1 = q1; p2 = q2; p3 = q3; }
    float c0 = fmaf(w0,p3, fmaf(w1,p2, fmaf(w2,p1, fmaf(w3,o0, bb))));
    float c1 = fmaf(w0,p2, fmaf(w1,p1, fmaf(w2,o0, fmaf(w3,o1, bb))));
    float c2 = fmaf(w0,p1, fmaf(w1,o0, fmaf(w2,o1, fmaf(w3,o2, bb))));
    float c3 = fmaf(w0,o0, fmaf(w1,o1, fmaf(w2,o2, fmaf(w3,o3, bb))));
    sv[tt][0] = c0 / (1.f + expf(-c0));
    sv[tt][1] = c1 / (1.f + expf(-c1));
    sv[tt][2] = c2 / (1.f + expf(-c2));
    sv[tt][3] = c3 / (1.f + expf(-c3));
    ushort4v xq = { f2b(sv[tt][0]), f2b(sv[tt][1]), f2b(sv[tt][2]), f2b(sv[tt][3]) };
    *(ushort4v*)&S_.Xt[n][t0] = xq;
  }

  // ---- conv + silu for B/C channels (in-register; ew via shfl) ----
  {
    float ew0 = __shfl(ewl, t0+0), ew1 = __shfl(ewl, t0+1);
    float ew2 = __shfl(ewl, t0+2), ew3 = __shfl(ewl, t0+3);
#pragma unroll
    for (int tt=0; tt<4; tt++){
      const int nf = tt*16 + lane15;                 // 0..63 over B(0..31)|C(32..63)
      const int gch = 128 + nf;
      const float w0 = conv_w[gch*4+0], w1 = conv_w[gch*4+1], w2 = conv_w[gch*4+2], w3 = conv_w[gch*4+3];
      const float bb = conv_b[gch];
      float o0 = pb[tt][0], o1 = pb[tt][1], o2 = pb[tt][2], o3 = pb[tt][3];
      float p1 = __shfl_up(o3, 16), p2 = __shfl_up(o2, 16), p3 = __shfl_up(o1, 16);
      float q1 = __shfl(hB[tt][3], 48+lane15);
      float q2 = __shfl(hB[tt][2], 48+lane15);
      float q3 = __shfl(hB[tt][1], 48+lane15);
      if (quad == 0){ p1 = q1; p2 = q2; p3 = q3; }
      float c0 = fmaf(w0,p3, fmaf(w1,p2, fmaf(w2,p1, fmaf(w3,o0, bb))));
      float c1 = fmaf(w0,p2, fmaf(w1,p1, fmaf(w2,o0, fmaf(w3,o1, bb))));
      float c2 = fmaf(w0,p1, fmaf(w1,o0, fmaf(w2,o1, fmaf(w3,o2, bb))));
      float c3 = fmaf(w0,o0, fmaf(w1,o1, fmaf(w2,o2, fmaf(w3,o3, bb))));
      float s0 = c0 / (1.f + expf(-c0));
      float s1 = c1 / (1.f + expf(-c1));
      float s2 = c2 / (1.f + expf(-c2));
      float s3 = c3 / (1.f + expf(-c3));
      if (tt < 2){                                   // B channels n = nf
        const int n = nf;
        S_.Bsh[t0+0][n] = f2b(s0);
        S_.Bsh[t0+1][n] = f2b(s1);
        S_.Bsh[t0+2][n] = f2b(s2);
        S_.Bsh[t0+3][n] = f2b(s3);
        ushort4v bq = { f2b(s0*ew0), f2b(s1*ew1), f2b(s2*ew2), f2b(s3*ew3) };
        *(ushort4v*)&S_.Bt[n][t0] = bq;
      } else {                                       // C channels n = nf-32
        const int n = nf - 32;
        S_.Csh[t0+0][n] = f2b(s0);
        S_.Csh[t0+1][n] = f2b(s1);
        S_.Csh[t0+2][n] = f2b(s2);
        S_.Csh[t0+3][n] = f2b(s3);
        if (h == 0){
          g_C[(row0+t0+0)*DSTATE + n] = f2b(s0);
          g_C[(row0+t0+1)*DSTATE + n] = f2b(s1);
          g_C[(row0+t0+2)*DSTATE + n] = f2b(s2);
          g_C[(row0+t0+3)*DSTATE + n] = f2b(s3);
        }
      }
    }
  }
  __syncthreads();   // barrier 1: Xt/Bsh/Csh/Bt visible

  // ---- SSD: G = C·B^T (lower-tri gate), Y = G·X + D*x, S = (ew B)^T·X ----
  short8 afr = *(const short8*)&S_.Csh[16*w + lane15][quad*8];
  f32x4 gacc[4];
#pragma unroll
  for (int tn=0;tn<4;tn++){
    short8 bfr = *(const short8*)&S_.Bsh[16*tn + lane15][quad*8];
    f32x4 z = {0.f,0.f,0.f,0.f};
    gacc[tn] = __builtin_amdgcn_mfma_f32_16x16x32_bf16(afr, bfr, z, 0, 0, 0);
  }
#pragma unroll
  for (int tn=0;tn<4;tn++){
    int s = 16*tn + lane15;
    float cs = __shfl(cum, s), ds = __shfl(dtv, s);
#pragma unroll
    for (int r=0;r<4;r++){
      int t = 16*w + quad*4 + r;
      float ct = __shfl(cum, t);
      float gv = 0.f;
      if (s <= t) gv = expf(ct-cs) * ds * gacc[tn][r];
      S_.Gsh[t][s] = f2b(gv);
    }
  }
  __syncthreads();   // barrier 2: Gsh visible
#pragma unroll
  for (int tn=0;tn<4;tn++){
    f32x4 acc = {0.f,0.f,0.f,0.f};
#pragma unroll
    for (int ks=0;ks<2;ks++){
      short8 a  = *(const short8*)&S_.Gsh[16*w  + lane15][quad*8 + 32*ks];
      short8 bf = *(const short8*)&S_.Xt [16*tn + lane15][quad*8 + 32*ks];
      acc = __builtin_amdgcn_mfma_f32_16x16x32_bf16(a, bf, acc, 0, 0, 0);
    }
    int p = 16*tn + lane15;
#pragma unroll
    for (int r=0;r<4;r++){
      int t = 16*w + quad*4 + r;
      g_y[(row0+t)*DINNER + h*HEADDIM + p] = acc[r] + dph * sv[tn][r];  // exact fp32 fold
    }
  }
  const size_t sb = (size_t)((b*NHEADS+h)*NCHUNK + ch) * (DSTATE*HEADDIM);
  const int tm2 = w & 1, tnb = (w>>1)*2;
#pragma unroll
  for (int tt=0;tt<2;tt++){
    int tn2 = tnb + tt;
    f32x4 acc = {0.f,0.f,0.f,0.f};
#pragma unroll
    for (int ks=0;ks<2;ks++){
      short8 a  = *(const short8*)&S_.Bt[16*tm2 + lane15][quad*8 + 32*ks];
      short8 bf = *(const short8*)&S_.Xt[16*tn2 + lane15][quad*8 + 32*ks];
      acc = __builtin_amdgcn_mfma_f32_16x16x32_bf16(a, bf, acc, 0, 0, 0);
    }
    int p = 16*tn2 + lane15;
#pragma unroll
    for (int r=0;r<4;r++){
      int n = 16*tm2 + quad*4 + r;
      g_S[sb + n*HEADDIM + p] = acc[r];
    }
  }
}

// ---- K5: sequential-over-chunks state scan (software-pipelined, bit-identical chain) ----
__global__ __launch_bounds__(256) void k_chunkScan() {
  __shared__ float dAc[NCHUNK];            // exp(ctot) per chunk (uniform per block)
  const int idx = blockIdx.x*256 + threadIdx.x;
  const int np = idx & 2047;
  const int bh = idx >> 11;                // uniform within a 256-thread block
  if (threadIdx.x < NCHUNK) dAc[threadIdx.x] = expf(g_ctot[bh*NCHUNK + threadIdx.x]);
  __syncthreads();
  float h = 0.f;
  const size_t base = (size_t)bh*NCHUNK*2048 + np;
#pragma unroll 1
  for (int k0=0; k0<NCHUNK; k0+=8){
    float s[8];
#pragma unroll
    for (int j=0;j<8;j++) s[j] = g_S[base + (size_t)(k0+j)*2048];   // 8 independent loads
    float hs[8];
#pragma unroll
    for (int j=0;j<8;j++){
      hs[j] = h;                                                     // state at chunk start
      h = h*dAc[k0+j] + s[j];                                        // same chain order
    }
#pragma unroll
    for (int j=0;j<8;j++) g_H[base + (size_t)(k0+j)*2048] = hs[j];
  }
}

// ---- K6 (fused): inter-chunk y + gate + RMSNorm + split-MFMA out_proj ----
// Epilogue: per-wave LDS transpose (reusing yAh) -> 4KB contiguous row stores.
__global__ __launch_bounds__(256,3) void k_fusedC(const unsigned short* __restrict__ WoutTh,
                                                  const unsigned short* __restrict__ WoutTl,
                                                  float* __restrict__ dout, int dsel) {
  __shared__ float Cl[QC][DSTATE+1];             // 8.4 KB
  __shared__ float ec[NHEADS][QC];
  __shared__ unsigned short yAh[64][136];        // 17.4 KB (reused as store staging)
  __shared__ unsigned short yAl[64][136];        // 17.4 KB
  float* __restrict__ out = (dsel==0) ? g_ping0 : (dsel==1 ? g_ping1 : dout);
  const int bx = blockIdx.x; const int b = bx>>6, ch = bx&63;
  const int tid = threadIdx.x;
  const size_t row0 = (size_t)b*SEQ + (size_t)ch*QC;
  const int w = tid>>6, l = tid&63, lane15 = l&15, quad = l>>4;
#pragma unroll
  for (int j=0;j<8;j++){ int e=tid+j*256; int s=e>>5, n=e&31;
    Cl[s][n] = b2f(g_C[(row0+s)*DSTATE + n]); }
  if (tid < 128){ int h_=tid>>6, s=tid&63;
    ec[h_][s] = expf(g_cum[(b*NHEADS+h_)*SEQ + ch*QC + s]); }
  float hr[64];
  {
    const float* H0 = &g_H[(size_t)((b*NHEADS+0)*NCHUNK + ch)*2048];
    const float* H1 = &g_H[(size_t)((b*NHEADS+1)*NCHUNK + ch)*2048];
#pragma unroll
    for (int n=0;n<32;n++){ hr[n] = H0[n*64 + l]; hr[32+n] = H1[n*64 + l]; }
  }
  __syncthreads();
#pragma unroll 1
  for (int i=0;i<16;i++){
    const int r = 16*w + i;
    const size_t row = row0 + r;
    float d0 = 0.f, d1 = 0.f;
#pragma unroll
    for (int n=0;n<32;n++){
      float c = Cl[r][n];
      d0 = fmaf(c, hr[n],    d0);
      d1 = fmaf(c, hr[32+n], d1);
    }
    float yv0 = g_y[row*DINNER + l]      + ec[0][r]*d0;
    float yv1 = g_y[row*DINNER + l + 64] + ec[1][r]*d1;
    float z0 = g_z[row*DINNER + l];
    float z1 = g_z[row*DINNER + l + 64];
    yv0 *= z0 / (1.f + expf(-z0));
    yv1 *= z1 / (1.f + expf(-z1));
    float ss = yv0*yv0 + yv1*yv1;
#pragma unroll
    for (int off=32; off>=1; off>>=1) ss += __shfl_xor(ss, off);
    float sc = rsqrtf(ss*(1.f/128.f) + 1e-5f);
    split2(yv0*sc, yAh[r][l],    yAl[r][l]);
    split2(yv1*sc, yAh[r][l+64], yAl[r][l+64]);
  }
  __syncthreads();
  short8 afh[4], afl[4];
#pragma unroll
  for (int ks=0;ks<4;ks++){
    afh[ks] = *(const short8*)&yAh[16*w + lane15][quad*8 + 32*ks];
    afl[ks] = *(const short8*)&yAl[16*w + lane15][quad*8 + 32*ks];
  }
  __syncthreads();   // all yAh reads done; reuse as per-wave staging
  float (*stgF)[68] = (float(*)[68])((float*)&yAh[0][0] + (size_t)w*16*68);
#pragma unroll
  for (int tc=0;tc<4;tc++){
    f32x4 acc = {0.f,0.f,0.f,0.f};
#pragma unroll
    for (int ks=0;ks<4;ks++){
      const unsigned short* bph = &WoutTh[(16*tc + lane15)*DINNER + quad*8 + 32*ks];
      const unsigned short* bpl = &WoutTl[(16*tc + lane15)*DINNER + quad*8 + 32*ks];
      short8 bh  = *(const short8*)bph;
      short8 blo = *(const short8*)bpl;
      acc = __builtin_amdgcn_mfma_f32_16x16x32_bf16(afh[ks], bh,  acc, 0, 0, 0);
      acc = __builtin_amdgcn_mfma_f32_16x16x32_bf16(afl[ks], bh,  acc, 0, 0, 0);
      acc = __builtin_amdgcn_mfma_f32_16x16x32_bf16(afh[ks], blo, acc, 0, 0, 0);
    }
#pragma unroll
    for (int r=0;r<4;r++)
      stgF[quad*4+r][tc*16+lane15] = acc[r];
  }
#pragma unroll
  for (int it=0; it<4; it++){
    int e = it*64 + l;
    int lr = e>>4, c4 = (e&15)<<2;
    float4 v = *(const float4*)&stgF[lr][c4];
    *(float4*)&out[(row0 + 16*w + lr)*DMODEL + c4] = v;
  }
}

extern "C" void kernel_launch(void* const* d_in, const int* in_sizes, int n_in,
                              void* d_out, int out_size, void* d_ws, size_t ws_size,
                              hipStream_t stream) {
  (void)in_sizes; (void)n_in; (void)d_ws; (void)ws_size; (void)out_size;
  const float* x       = (const float*)d_in[0];
  const float* Win     = (const float*)d_in[1];
  const float* conv_w  = (const float*)d_in[2];
  const float* conv_b  = (const float*)d_in[3];
  const float* dt_bias = (const float*)d_in[4];
  const float* A_log   = (const float*)d_in[5];
  const float* Dp      = (const float*)d_in[6];
  const float* norm_w  = (const float*)d_in[7];
  const float* Wout    = (const float*)d_in[8];

  k_prep<<<(8*(NPAD*DMODEL + DMODEL*DINNER) + 255)/256, 256, 0, stream>>>(Win, Wout, norm_w);

  unsigned short *winTh, *winTl, *woutTh, *woutTl;
  hipGetSymbolAddress((void**)&winTh,  HIP_SYMBOL(g_WinTh));
  hipGetSymbolAddress((void**)&winTl,  HIP_SYMBOL(g_WinTl));
  hipGetSymbolAddress((void**)&woutTh, HIP_SYMBOL(g_WoutTh));
  hipGetSymbolAddress((void**)&woutTl, HIP_SYMBOL(g_WoutTl));

  for (int layer = 0; layer < 8; ++layer) {
    const int insel = (layer==0) ? 0 : ((((layer-1)&1)==0) ? 1 : 2);
    const int dsel  = (layer==7) ? 2 : ((layer&1)==0 ? 0 : 1);

    k_fusedAB<<<BATCH*NHEADS*NCHUNK, 256, 0, stream>>>(x, insel,
                                        winTh + (size_t)layer*NPAD*DMODEL,
                                        winTl + (size_t)layer*NPAD*DMODEL,
                                        Win + (size_t)layer*DMODEL*PROJ,
                                        dt_bias + layer*NHEADS, A_log + layer*NHEADS,
                                        conv_w + (size_t)layer*CONVDIM*4,
                                        conv_b + (size_t)layer*CONVDIM,
                                        Dp + layer*NHEADS);
    k_chunkScan<<<(BATCH*NHEADS*DSTATE*HEADDIM)/256, 256, 0, stream>>>();
    k_fusedC<<<BATCH*NCHUNK, 256, 0, stream>>>(woutTh + (size_t)layer*DMODEL*DINNER,
                                               woutTl + (size_t)layer*DMODEL*DINNER,
                                               (float*)d_out, dsel);
  }
}

// Round 5
// 1161.180 us; speedup vs baseline: 1.2140x; 1.2140x over previous
//
#include <hip/hip_runtime.h>
#include <math.h>

// ---- problem constants ----
#define BATCH   16
#define SEQ     4096
#define DMODEL  64
#define DINNER  128
#define DSTATE  32
#define NHEADS  2
#define HEADDIM 64
#define CONVDIM 192            // DINNER + 2*DSTATE
#define PROJ    322            // 2*DINNER + 2*DSTATE + NHEADS
#define QC      64             // chunk length for SSD scan
#define NCHUNK  (SEQ/QC)       // 64
#define BL      (BATCH*SEQ)    // 65536 rows
#define NPAD    336            // PROJ padded to 21*16 for MFMA col tiles

typedef __attribute__((ext_vector_type(8))) short short8;   // 8 bf16 (4 VGPRs)
typedef __attribute__((ext_vector_type(4))) float f32x4;    // MFMA C/D
typedef __attribute__((ext_vector_type(4))) unsigned short ushort4v;

__device__ inline unsigned short f2b(float f){
  union { float f; unsigned u; } v; v.f = f;
  unsigned r = v.u + 0x7FFF + ((v.u >> 16) & 1);   // round-to-nearest-even
  return (unsigned short)(r >> 16);
}
__device__ inline float b2f(unsigned short s){
  union { unsigned u; float f; } v; v.u = ((unsigned)s) << 16; return v.f;
}
// hi/lo split: x ~= hi + lo, residual ~2^-18 * x
__device__ inline void split2(float x, unsigned short& h, unsigned short& l){
  unsigned short hh = f2b(x);
  h = hh;
  l = f2b(x - b2f(hh));
}

// ---- static device scratch ----
// fp32 on the cross-kernel signal path (R5/R6 post-mortem: bf16 there fails).
__device__ float g_z   [(size_t)BL*DINNER];    // z (dense fp32)
__device__ float g_y   [(size_t)BL*DINNER];    // y_intra + D*x (fp32, exact fold)
__device__ unsigned short g_C[(size_t)BL*DSTATE]; // post-conv C (bf16)
__device__ float g_cum [BATCH*NHEADS*SEQ];
__device__ float g_ctot[BATCH*NHEADS*NCHUNK];
__device__ float g_S   [BATCH*NHEADS*NCHUNK*DSTATE*HEADDIM];
__device__ float g_H   [BATCH*NHEADS*NCHUNK*DSTATE*HEADDIM];
__device__ float g_ping0[(size_t)BL*DMODEL];
__device__ float g_ping1[(size_t)BL*DMODEL];
__device__ unsigned short g_WinTh [8*NPAD*DMODEL];
__device__ unsigned short g_WinTl [8*NPAD*DMODEL];
__device__ unsigned short g_WoutTh[8*DMODEL*DINNER];
__device__ unsigned short g_WoutTl[8*DMODEL*DINNER];

// ---- K0: prep transposed hi/lo bf16 weights ----
__global__ __launch_bounds__(256) void k_prep(const float* __restrict__ Win,
                                              const float* __restrict__ Wout,
                                              const float* __restrict__ normw) {
  const int idx = blockIdx.x*256 + threadIdx.x;
  const int NW = 8*NPAD*DMODEL;
  if (idx < NW) {
    int layer = idx / (NPAD*DMODEL);
    int rem   = idx - layer*(NPAD*DMODEL);
    int n = rem >> 6, k = rem & 63;
    float v = (n < PROJ) ? Win[(size_t)layer*DMODEL*PROJ + k*PROJ + n] : 0.f;
    split2(v, g_WinTh[idx], g_WinTl[idx]);
  } else {
    int i2 = idx - NW;
    if (i2 < 8*DMODEL*DINNER) {
      int layer = i2 / (DMODEL*DINNER);
      int rem   = i2 - layer*(DMODEL*DINNER);
      int n = rem >> 7, k = rem & 127;
      float v = Wout[(size_t)layer*DINNER*DMODEL + k*DMODEL + n] * normw[layer*DINNER + k];
      split2(v, g_WoutTh[i2], g_WoutTl[i2]);
    }
  }
}

// ---- K17 (fused inproj + chunkA), per (b,h,ch) block ----
// R17 = R15 structure minus its stalls:
//  - dt matvec from the already-loaded A-fragment values (16 fmaf + 2 shfl_xor),
//    partials -> tiny dtraw LDS; post-bar1 every wave runs the cheap register
//    shfl-scan (no scatter loads, no wave-0 serialization).
//  - R15's shared halo via Hl (2 MFMA6/wave), NOT R16's per-wave recompute.
//  - z stored directly from MFMA layout (no staging barrier / conflicts).
//  - barriers 6 -> 4. LDS 32.5 KB + launch_bounds(256,4) -> 4 blocks/CU.
__global__ __launch_bounds__(256,4) void k_fusedAB(const float* __restrict__ xext, int sel,
                                                   const unsigned short* __restrict__ WinTh,
                                                   const unsigned short* __restrict__ WinTl,
                                                   const float* __restrict__ Win,
                                                   const float* __restrict__ dt_bias,
                                                   const float* __restrict__ A_log,
                                                   const float* __restrict__ conv_w,
                                                   const float* __restrict__ conv_b,
                                                   const float* __restrict__ Dp) {
  __shared__ struct {
    unsigned short Xt [64][72];        // X^T bf16 (9216 B)
    unsigned short Bt [32][72];        // (ew*B)^T bf16 (4608 B)
    float Hl[2][5][3][68];             // pre-conv halo rows (8160 B)
    union {
      struct { unsigned short Bsh[64][40]; unsigned short Csh[64][40]; } bc; // 10240 B
      unsigned short Gsh[64][72];                                            // 9216 B
    } u;
    float dtraw[64];                   // 256 B
  } S_;                                // 32,480 B total

  const float* __restrict__ X = (sel==0) ? xext : (sel==1 ? g_ping0 : g_ping1);
  const int bx = blockIdx.x; const int b = bx>>7, h = (bx>>6)&1, ch = bx&63;
  const int tid = threadIdx.x;
  const int w = tid>>6, l = tid&63, lane15 = l&15, quad = l>>4;
  const size_t row0 = (size_t)b*SEQ + (size_t)ch*QC;
  const int cbase = (b*NHEADS+h)*SEQ + ch*QC;
  const float dph = Dp[h];

  // ---- main A fragments (rows row0+16w+lane15), in-register split ----
  const float* xrow = &X[(row0 + 16*w + lane15)*DMODEL + quad*8];
  float4 f0 = *(const float4*)(xrow);
  float4 f1 = *(const float4*)(xrow + 4);
  float4 f2 = *(const float4*)(xrow + 32);
  float4 f3 = *(const float4*)(xrow + 36);
  short8 a0h, a0l, a1h, a1l;
  float v0[8] = {f0.x,f0.y,f0.z,f0.w,f1.x,f1.y,f1.z,f1.w};
  float v1[8] = {f2.x,f2.y,f2.z,f2.w,f3.x,f3.y,f3.z,f3.w};
  {
    unsigned short hh, ll;
#pragma unroll
    for (int j=0;j<8;j++){ split2(v0[j], hh, ll); a0h[j]=(short)hh; a0l[j]=(short)ll; }
#pragma unroll
    for (int j=0;j<8;j++){ split2(v1[j], hh, ll); a1h[j]=(short)hh; a1l[j]=(short)ll; }
  }

  // ---- dt partial dot from fragment values (coalesced inputs, no scatter) ----
  {
    const float* wd = &Win[DINNER + CONVDIM + h];   // Win[k*PROJ + dtcol]
    float p = 0.f;
#pragma unroll
    for (int j=0;j<8;j++) p = fmaf(v0[j], wd[(quad*8+j)*PROJ], p);
#pragma unroll
    for (int j=0;j<8;j++) p = fmaf(v1[j], wd[(32+quad*8+j)*PROJ], p);
    p += __shfl_xor(p, 16);
    p += __shfl_xor(p, 32);
    if (quad == 0) S_.dtraw[16*w + lane15] = p;     // full dot for row 16w+lane15
  }

  // 6-MFMA split-precision tile (identical op order to R12/R15)
  auto MFMA6 = [&](short8 A0h, short8 A1h, short8 A0l, short8 A1l, int t)->f32x4 {
    const unsigned short* bph = &WinTh[(16*t + lane15)*64 + quad*8];
    const unsigned short* bpl = &WinTl[(16*t + lane15)*64 + quad*8];
    short8 b0h = *(const short8*)bph;
    short8 b1h = *(const short8*)(bph + 32);
    short8 b0l = *(const short8*)bpl;
    short8 b1l = *(const short8*)(bpl + 32);
    f32x4 acc = {0.f,0.f,0.f,0.f};
    acc = __builtin_amdgcn_mfma_f32_16x16x32_bf16(A0h, b0h, acc, 0, 0, 0);
    acc = __builtin_amdgcn_mfma_f32_16x16x32_bf16(A1h, b1h, acc, 0, 0, 0);
    acc = __builtin_amdgcn_mfma_f32_16x16x32_bf16(A0l, b0h, acc, 0, 0, 0);
    acc = __builtin_amdgcn_mfma_f32_16x16x32_bf16(A1l, b1h, acc, 0, 0, 0);
    acc = __builtin_amdgcn_mfma_f32_16x16x32_bf16(A0h, b0l, acc, 0, 0, 0);
    acc = __builtin_amdgcn_mfma_f32_16x16x32_bf16(A1h, b1l, acc, 0, 0, 0);
    return acc;
  };

  // ---- halo tiles (R15 sharing scheme: wave w computes prev-chunk tile-col w) ----
  if (ch != 0){
    const float* xh = &X[(row0 - 16 + lane15)*DMODEL + quad*8];
    float4 g0 = *(const float4*)(xh);
    float4 g1 = *(const float4*)(xh + 4);
    float4 g2 = *(const float4*)(xh + 32);
    float4 g3 = *(const float4*)(xh + 36);
    short8 e0h, e0l, e1h, e1l;
    {
      float u0[8] = {g0.x,g0.y,g0.z,g0.w,g1.x,g1.y,g1.z,g1.w};
      float u1[8] = {g2.x,g2.y,g2.z,g2.w,g3.x,g3.y,g3.z,g3.w};
      unsigned short hh, ll;
#pragma unroll
      for (int j=0;j<8;j++){ split2(u0[j], hh, ll); e0h[j]=(short)hh; e0l[j]=(short)ll; }
#pragma unroll
      for (int j=0;j<8;j++){ split2(u1[j], hh, ll); e1h[j]=(short)hh; e1l[j]=(short)ll; }
    }
    f32x4 hA = MFMA6(e0h, e1h, e0l, e1l, 8+4*h+w);   // x-half halo tile (cols 16w..)
    f32x4 hB = MFMA6(e0h, e1h, e0l, e1l, 16+w);      // B/C halo tile
    if (quad == 3){
#pragma unroll
      for (int r=1;r<4;r++){
        S_.Hl[0][4][r-1][w*16+lane15] = hA[r];       // prev rows 61..63
        S_.Hl[1][4][r-1][w*16+lane15] = hB[r];
      }
    }
  } else if (tid < 192) {
    int j = tid>>6, n = tid&63;
    S_.Hl[0][4][j][n] = 0.f;
    S_.Hl[1][4][j][n] = 0.f;
  }

  // ---- z tiles: direct stores from MFMA layout (no staging, no barrier) ----
  {
#pragma unroll
    for (int tt=0; tt<4; tt++){
      f32x4 az = MFMA6(a0h, a1h, a0l, a1l, 4*h+tt);
#pragma unroll
      for (int r=0;r<4;r++)
        g_z[(row0 + 16*w + quad*4 + r)*DINNER + h*64 + tt*16 + lane15] = az[r];
    }
  }

  // ---- main pass tiles; quad3 rows 13..15 -> Hl for the next wave ----
  f32x4 pa[4];
#pragma unroll
  for (int tt=0; tt<4; tt++) pa[tt] = MFMA6(a0h, a1h, a0l, a1l, 8+4*h+tt);
  if (quad == 3){
#pragma unroll
    for (int tt=0; tt<4; tt++)
#pragma unroll
      for (int r=1;r<4;r++)
        S_.Hl[0][w][r-1][tt*16+lane15] = pa[tt][r];
  }
  f32x4 pb[4];
#pragma unroll
  for (int tt=0; tt<4; tt++) pb[tt] = MFMA6(a0h, a1h, a0l, a1l, 16+tt);
  if (quad == 3){
#pragma unroll
    for (int tt=0; tt<4; tt++)
#pragma unroll
      for (int r=1;r<4;r++)
        S_.Hl[1][w][r-1][tt*16+lane15] = pb[tt][r];
  }
  __syncthreads();   // barrier 1: Hl, dtraw visible

  // ---- dt scan, register-resident in every wave (identical chain) ----
  float cum, dtv, ewl;
  {
    float dr = S_.dtraw[l];
    float xv = dr + dt_bias[h];
    dtv = (xv > 20.f) ? xv : log1pf(expf(xv));
    float A = -expf(A_log[h]);
    cum = dtv * A;
#pragma unroll
    for (int off=1; off<64; off<<=1){
      float v = __shfl_up(cum, off);
      if (l >= off) cum += v;
    }
    if (w == 0){
      g_cum[cbase+l] = cum;
      if (l == 63) g_ctot[(b*NHEADS+h)*NCHUNK + ch] = cum;
    }
    float cl = __shfl(cum, 63);
    ewl = expf(cl - cum) * dtv;
  }

  const int t0 = 16*w + quad*4;

  // ---- conv + silu for x channels (in-register; quad0 halo from Hl) ----
  float sv[4][4];    // silu(x) at (t0+r, 16tt+lane15) — feeds Xt AND the Y-fold
#pragma unroll
  for (int tt=0; tt<4; tt++){
    const int n = tt*16 + lane15;
    const int gch = h*64 + n;
    const float w0 = conv_w[gch*4+0], w1 = conv_w[gch*4+1], w2 = conv_w[gch*4+2], w3 = conv_w[gch*4+3];
    const float bb = conv_b[gch];
    float o0 = pa[tt][0], o1 = pa[tt][1], o2 = pa[tt][2], o3 = pa[tt][3];
    float p1 = __shfl_up(o3, 16), p2 = __shfl_up(o2, 16), p3 = __shfl_up(o1, 16);
    if (quad == 0){
      const int slot = (w==0) ? 4 : (w-1);
      p1 = S_.Hl[0][slot][2][n];
      p2 = S_.Hl[0][slot][1][n];
      p3 = S_.Hl[0][slot][0][n];
    }
    float c0 = fmaf(w0,p3, fmaf(w1,p2, fmaf(w2,p1, fmaf(w3,o0, bb))));
    float c1 = fmaf(w0,p2, fmaf(w1,p1, fmaf(w2,o0, fmaf(w3,o1, bb))));
    float c2 = fmaf(w0,p1, fmaf(w1,o0, fmaf(w2,o1, fmaf(w3,o2, bb))));
    float c3 = fmaf(w0,o0, fmaf(w1,o1, fmaf(w2,o2, fmaf(w3,o3, bb))));
    sv[tt][0] = c0 / (1.f + expf(-c0));
    sv[tt][1] = c1 / (1.f + expf(-c1));
    sv[tt][2] = c2 / (1.f + expf(-c2));
    sv[tt][3] = c3 / (1.f + expf(-c3));
    ushort4v xq = { f2b(sv[tt][0]), f2b(sv[tt][1]), f2b(sv[tt][2]), f2b(sv[tt][3]) };
    *(ushort4v*)&S_.Xt[n][t0] = xq;
  }

  // ---- conv + silu for B/C channels (in-register; ew via shfl) ----
  {
    float ew0 = __shfl(ewl, t0+0), ew1 = __shfl(ewl, t0+1);
    float ew2 = __shfl(ewl, t0+2), ew3 = __shfl(ewl, t0+3);
#pragma unroll
    for (int tt=0; tt<4; tt++){
      const int nf = tt*16 + lane15;                 // 0..63 over B(0..31)|C(32..63)
      const int gch = 128 + nf;
      const float w0 = conv_w[gch*4+0], w1 = conv_w[gch*4+1], w2 = conv_w[gch*4+2], w3 = conv_w[gch*4+3];
      const float bb = conv_b[gch];
      float o0 = pb[tt][0], o1 = pb[tt][1], o2 = pb[tt][2], o3 = pb[tt][3];
      float p1 = __shfl_up(o3, 16), p2 = __shfl_up(o2, 16), p3 = __shfl_up(o1, 16);
      if (quad == 0){
        const int slot = (w==0) ? 4 : (w-1);
        p1 = S_.Hl[1][slot][2][nf];
        p2 = S_.Hl[1][slot][1][nf];
        p3 = S_.Hl[1][slot][0][nf];
      }
      float c0 = fmaf(w0,p3, fmaf(w1,p2, fmaf(w2,p1, fmaf(w3,o0, bb))));
      float c1 = fmaf(w0,p2, fmaf(w1,p1, fmaf(w2,o0, fmaf(w3,o1, bb))));
      float c2 = fmaf(w0,p1, fmaf(w1,o0, fmaf(w2,o1, fmaf(w3,o2, bb))));
      float c3 = fmaf(w0,o0, fmaf(w1,o1, fmaf(w2,o2, fmaf(w3,o3, bb))));
      float s0 = c0 / (1.f + expf(-c0));
      float s1 = c1 / (1.f + expf(-c1));
      float s2 = c2 / (1.f + expf(-c2));
      float s3 = c3 / (1.f + expf(-c3));
      if (tt < 2){                                   // B channels n = nf
        const int n = nf;
        S_.u.bc.Bsh[t0+0][n] = f2b(s0);
        S_.u.bc.Bsh[t0+1][n] = f2b(s1);
        S_.u.bc.Bsh[t0+2][n] = f2b(s2);
        S_.u.bc.Bsh[t0+3][n] = f2b(s3);
        ushort4v bq = { f2b(s0*ew0), f2b(s1*ew1), f2b(s2*ew2), f2b(s3*ew3) };
        *(ushort4v*)&S_.Bt[n][t0] = bq;
      } else {                                       // C channels n = nf-32
        const int n = nf - 32;
        S_.u.bc.Csh[t0+0][n] = f2b(s0);
        S_.u.bc.Csh[t0+1][n] = f2b(s1);
        S_.u.bc.Csh[t0+2][n] = f2b(s2);
        S_.u.bc.Csh[t0+3][n] = f2b(s3);
        if (h == 0){
          g_C[(row0+t0+0)*DSTATE + n] = f2b(s0);
          g_C[(row0+t0+1)*DSTATE + n] = f2b(s1);
          g_C[(row0+t0+2)*DSTATE + n] = f2b(s2);
          g_C[(row0+t0+3)*DSTATE + n] = f2b(s3);
        }
      }
    }
  }
  __syncthreads();   // barrier 2: Xt/Bsh/Csh/Bt visible

  // ---- SSD: G = C·B^T (lower-tri gate), Y = G·X + D*x, S = (ew B)^T·X ----
  short8 afr = *(const short8*)&S_.u.bc.Csh[16*w + lane15][quad*8];
  f32x4 gacc[4];
#pragma unroll
  for (int tn=0;tn<4;tn++){
    short8 bfr = *(const short8*)&S_.u.bc.Bsh[16*tn + lane15][quad*8];
    f32x4 z = {0.f,0.f,0.f,0.f};
    gacc[tn] = __builtin_amdgcn_mfma_f32_16x16x32_bf16(afr, bfr, z, 0, 0, 0);
  }
  __syncthreads();   // barrier 3: Bsh/Csh reads done before Gsh (aliased) writes
#pragma unroll
  for (int tn=0;tn<4;tn++){
    int s = 16*tn + lane15;
    float cs = __shfl(cum, s), ds = __shfl(dtv, s);
#pragma unroll
    for (int r=0;r<4;r++){
      int t = 16*w + quad*4 + r;
      float ct = __shfl(cum, t);
      float gv = 0.f;
      if (s <= t) gv = expf(ct-cs) * ds * gacc[tn][r];
      S_.u.Gsh[t][s] = f2b(gv);
    }
  }
  __syncthreads();   // barrier 4: Gsh visible
#pragma unroll
  for (int tn=0;tn<4;tn++){
    f32x4 acc = {0.f,0.f,0.f,0.f};
#pragma unroll
    for (int ks=0;ks<2;ks++){
      short8 a  = *(const short8*)&S_.u.Gsh[16*w  + lane15][quad*8 + 32*ks];
      short8 bf = *(const short8*)&S_.Xt  [16*tn + lane15][quad*8 + 32*ks];
      acc = __builtin_amdgcn_mfma_f32_16x16x32_bf16(a, bf, acc, 0, 0, 0);
    }
    int p = 16*tn + lane15;
#pragma unroll
    for (int r=0;r<4;r++){
      int t = 16*w + quad*4 + r;
      g_y[(row0+t)*DINNER + h*HEADDIM + p] = acc[r] + dph * sv[tn][r];  // exact fp32 fold
    }
  }
  const size_t sb = (size_t)((b*NHEADS+h)*NCHUNK + ch) * (DSTATE*HEADDIM);
  const int tm2 = w & 1, tnb = (w>>1)*2;
#pragma unroll
  for (int tt=0;tt<2;tt++){
    int tn2 = tnb + tt;
    f32x4 acc = {0.f,0.f,0.f,0.f};
#pragma unroll
    for (int ks=0;ks<2;ks++){
      short8 a  = *(const short8*)&S_.Bt[16*tm2 + lane15][quad*8 + 32*ks];
      short8 bf = *(const short8*)&S_.Xt[16*tn2 + lane15][quad*8 + 32*ks];
      acc = __builtin_amdgcn_mfma_f32_16x16x32_bf16(a, bf, acc, 0, 0, 0);
    }
    int p = 16*tn2 + lane15;
#pragma unroll
    for (int r=0;r<4;r++){
      int n = 16*tm2 + quad*4 + r;
      g_S[sb + n*HEADDIM + p] = acc[r];
    }
  }
}

// ---- K5: sequential-over-chunks state scan (software-pipelined, bit-identical chain) ----
__global__ __launch_bounds__(256) void k_chunkScan() {
  __shared__ float dAc[NCHUNK];            // exp(ctot) per chunk (uniform per block)
  const int idx = blockIdx.x*256 + threadIdx.x;
  const int np = idx & 2047;
  const int bh = idx >> 11;                // uniform within a 256-thread block
  if (threadIdx.x < NCHUNK) dAc[threadIdx.x] = expf(g_ctot[bh*NCHUNK + threadIdx.x]);
  __syncthreads();
  float h = 0.f;
  const size_t base = (size_t)bh*NCHUNK*2048 + np;
#pragma unroll 1
  for (int k0=0; k0<NCHUNK; k0+=8){
    float s[8];
#pragma unroll
    for (int j=0;j<8;j++) s[j] = g_S[base + (size_t)(k0+j)*2048];   // 8 independent loads
    float hs[8];
#pragma unroll
    for (int j=0;j<8;j++){
      hs[j] = h;                                                     // state at chunk start
      h = h*dAc[k0+j] + s[j];                                        // same chain order
    }
#pragma unroll
    for (int j=0;j<8;j++) g_H[base + (size_t)(k0+j)*2048] = hs[j];
  }
}

// ---- K6 (fused): inter-chunk y + gate + RMSNorm + split-MFMA out_proj ----
// Epilogue: per-wave LDS transpose (reusing yAh) -> 4KB contiguous row stores.
__global__ __launch_bounds__(256,3) void k_fusedC(const unsigned short* __restrict__ WoutTh,
                                                  const unsigned short* __restrict__ WoutTl,
                                                  float* __restrict__ dout, int dsel) {
  __shared__ float Cl[QC][DSTATE+1];             // 8.4 KB
  __shared__ float ec[NHEADS][QC];
  __shared__ unsigned short yAh[64][136];        // 17.4 KB (reused as store staging)
  __shared__ unsigned short yAl[64][136];        // 17.4 KB
  float* __restrict__ out = (dsel==0) ? g_ping0 : (dsel==1 ? g_ping1 : dout);
  const int bx = blockIdx.x; const int b = bx>>6, ch = bx&63;
  const int tid = threadIdx.x;
  const size_t row0 = (size_t)b*SEQ + (size_t)ch*QC;
  const int w = tid>>6, l = tid&63, lane15 = l&15, quad = l>>4;
#pragma unroll
  for (int j=0;j<8;j++){ int e=tid+j*256; int s=e>>5, n=e&31;
    Cl[s][n] = b2f(g_C[(row0+s)*DSTATE + n]); }
  if (tid < 128){ int h_=tid>>6, s=tid&63;
    ec[h_][s] = expf(g_cum[(b*NHEADS+h_)*SEQ + ch*QC + s]); }
  float hr[64];
  {
    const float* H0 = &g_H[(size_t)((b*NHEADS+0)*NCHUNK + ch)*2048];
    const float* H1 = &g_H[(size_t)((b*NHEADS+1)*NCHUNK + ch)*2048];
#pragma unroll
    for (int n=0;n<32;n++){ hr[n] = H0[n*64 + l]; hr[32+n] = H1[n*64 + l]; }
  }
  __syncthreads();
#pragma unroll 1
  for (int i=0;i<16;i++){
    const int r = 16*w + i;
    const size_t row = row0 + r;
    float d0 = 0.f, d1 = 0.f;
#pragma unroll
    for (int n=0;n<32;n++){
      float c = Cl[r][n];
      d0 = fmaf(c, hr[n],    d0);
      d1 = fmaf(c, hr[32+n], d1);
    }
    float yv0 = g_y[row*DINNER + l]      + ec[0][r]*d0;
    float yv1 = g_y[row*DINNER + l + 64] + ec[1][r]*d1;
    float z0 = g_z[row*DINNER + l];
    float z1 = g_z[row*DINNER + l + 64];
    yv0 *= z0 / (1.f + expf(-z0));
    yv1 *= z1 / (1.f + expf(-z1));
    float ss = yv0*yv0 + yv1*yv1;
#pragma unroll
    for (int off=32; off>=1; off>>=1) ss += __shfl_xor(ss, off);
    float sc = rsqrtf(ss*(1.f/128.f) + 1e-5f);
    split2(yv0*sc, yAh[r][l],    yAl[r][l]);
    split2(yv1*sc, yAh[r][l+64], yAl[r][l+64]);
  }
  __syncthreads();
  short8 afh[4], afl[4];
#pragma unroll
  for (int ks=0;ks<4;ks++){
    afh[ks] = *(const short8*)&yAh[16*w + lane15][quad*8 + 32*ks];
    afl[ks] = *(const short8*)&yAl[16*w + lane15][quad*8 + 32*ks];
  }
  __syncthreads();   // all yAh reads done; reuse as per-wave staging
  float (*stgF)[68] = (float(*)[68])((float*)&yAh[0][0] + (size_t)w*16*68);
#pragma unroll
  for (int tc=0;tc<4;tc++){
    f32x4 acc = {0.f,0.f,0.f,0.f};
#pragma unroll
    for (int ks=0;ks<4;ks++){
      const unsigned short* bph = &WoutTh[(16*tc + lane15)*DINNER + quad*8 + 32*ks];
      const unsigned short* bpl = &WoutTl[(16*tc + lane15)*DINNER + quad*8 + 32*ks];
      short8 bh  = *(const short8*)bph;
      short8 blo = *(const short8*)bpl;
      acc = __builtin_amdgcn_mfma_f32_16x16x32_bf16(afh[ks], bh,  acc, 0, 0, 0);
      acc = __builtin_amdgcn_mfma_f32_16x16x32_bf16(afl[ks], bh,  acc, 0, 0, 0);
      acc = __builtin_amdgcn_mfma_f32_16x16x32_bf16(afh[ks], blo, acc, 0, 0, 0);
    }
#pragma unroll
    for (int r=0;r<4;r++)
      stgF[quad*4+r][tc*16+lane15] = acc[r];
  }
#pragma unroll
  for (int it=0; it<4; it++){
    int e = it*64 + l;
    int lr = e>>4, c4 = (e&15)<<2;
    float4 v = *(const float4*)&stgF[lr][c4];
    *(float4*)&out[(row0 + 16*w + lr)*DMODEL + c4] = v;
  }
}

extern "C" void kernel_launch(void* const* d_in, const int* in_sizes, int n_in,
                              void* d_out, int out_size, void* d_ws, size_t ws_size,
                              hipStream_t stream) {
  (void)in_sizes; (void)n_in; (void)d_ws; (void)ws_size; (void)out_size;
  const float* x       = (const float*)d_in[0];
  const float* Win     = (const float*)d_in[1];
  const float* conv_w  = (const float*)d_in[2];
  const float* conv_b  = (const float*)d_in[3];
  const float* dt_bias = (const float*)d_in[4];
  const float* A_log   = (const float*)d_in[5];
  const float* Dp      = (const float*)d_in[6];
  const float* norm_w  = (const float*)d_in[7];
  const float* Wout    = (const float*)d_in[8];

  k_prep<<<(8*(NPAD*DMODEL + DMODEL*DINNER) + 255)/256, 256, 0, stream>>>(Win, Wout, norm_w);

  unsigned short *winTh, *winTl, *woutTh, *woutTl;
  hipGetSymbolAddress((void**)&winTh,  HIP_SYMBOL(g_WinTh));
  hipGetSymbolAddress((void**)&winTl,  HIP_SYMBOL(g_WinTl));
  hipGetSymbolAddress((void**)&woutTh, HIP_SYMBOL(g_WoutTh));
  hipGetSymbolAddress((void**)&woutTl, HIP_SYMBOL(g_WoutTl));

  for (int layer = 0; layer < 8; ++layer) {
    const int insel = (layer==0) ? 0 : ((((layer-1)&1)==0) ? 1 : 2);
    const int dsel  = (layer==7) ? 2 : ((layer&1)==0 ? 0 : 1);

    k_fusedAB<<<BATCH*NHEADS*NCHUNK, 256, 0, stream>>>(x, insel,
                                        winTh + (size_t)layer*NPAD*DMODEL,
                                        winTl + (size_t)layer*NPAD*DMODEL,
                                        Win + (size_t)layer*DMODEL*PROJ,
                                        dt_bias + layer*NHEADS, A_log + layer*NHEADS,
                                        conv_w + (size_t)layer*CONVDIM*4,
                                        conv_b + (size_t)layer*CONVDIM,
                                        Dp + layer*NHEADS);
    k_chunkScan<<<(BATCH*NHEADS*DSTATE*HEADDIM)/256, 256, 0, stream>>>();
    k_fusedC<<<BATCH*NCHUNK, 256, 0, stream>>>(woutTh + (size_t)layer*DMODEL*DINNER,
                                               woutTl + (size_t)layer*DMODEL*DINNER,
                                               (float*)d_out, dsel);
  }
}

// Round 6
// 1088.017 us; speedup vs baseline: 1.2956x; 1.0672x over previous
//
#include <hip/hip_runtime.h>
#include <math.h>

// ---- problem constants ----
#define BATCH   16
#define SEQ     4096
#define DMODEL  64
#define DINNER  128
#define DSTATE  32
#define NHEADS  2
#define HEADDIM 64
#define CONVDIM 192            // DINNER + 2*DSTATE
#define PROJ    322            // 2*DINNER + 2*DSTATE + NHEADS
#define QC      64             // chunk length for SSD scan
#define NCHUNK  (SEQ/QC)       // 64
#define BL      (BATCH*SEQ)    // 65536 rows
#define NPAD    336            // PROJ padded to 21*16 for MFMA col tiles

typedef __attribute__((ext_vector_type(8))) short short8;   // 8 bf16 (4 VGPRs)
typedef __attribute__((ext_vector_type(4))) float f32x4;    // MFMA C/D
typedef __attribute__((ext_vector_type(4))) unsigned short ushort4v;

__device__ inline unsigned short f2b(float f){
  union { float f; unsigned u; } v; v.f = f;
  unsigned r = v.u + 0x7FFF + ((v.u >> 16) & 1);   // round-to-nearest-even
  return (unsigned short)(r >> 16);
}
__device__ inline float b2f(unsigned short s){
  union { unsigned u; float f; } v; v.u = ((unsigned)s) << 16; return v.f;
}
// hi/lo split: x ~= hi + lo, residual ~2^-18 * x
__device__ inline void split2(float x, unsigned short& h, unsigned short& l){
  unsigned short hh = f2b(x);
  h = hh;
  l = f2b(x - b2f(hh));
}

// ---- static device scratch ----
// fp32 on the cross-kernel signal path (R5/R6 post-mortem: bf16 there fails).
__device__ float g_z   [(size_t)BL*DINNER];    // z (dense fp32)
__device__ float g_y   [(size_t)BL*DINNER];    // y_intra + D*x (fp32, exact fold)
__device__ unsigned short g_C[(size_t)BL*DSTATE]; // post-conv C (bf16)
__device__ float g_cum [BATCH*NHEADS*SEQ];
__device__ float g_ctot[BATCH*NHEADS*NCHUNK];
__device__ float g_S   [BATCH*NHEADS*NCHUNK*DSTATE*HEADDIM];
__device__ float g_H   [BATCH*NHEADS*NCHUNK*DSTATE*HEADDIM];
__device__ float g_ping0[(size_t)BL*DMODEL];
__device__ float g_ping1[(size_t)BL*DMODEL];
__device__ unsigned short g_WinTh [8*NPAD*DMODEL];
__device__ unsigned short g_WinTl [8*NPAD*DMODEL];
__device__ unsigned short g_WoutTh[8*DMODEL*DINNER];
__device__ unsigned short g_WoutTl[8*DMODEL*DINNER];

// ---- K0: prep transposed hi/lo bf16 weights ----
__global__ __launch_bounds__(256) void k_prep(const float* __restrict__ Win,
                                              const float* __restrict__ Wout,
                                              const float* __restrict__ normw) {
  const int idx = blockIdx.x*256 + threadIdx.x;
  const int NW = 8*NPAD*DMODEL;
  if (idx < NW) {
    int layer = idx / (NPAD*DMODEL);
    int rem   = idx - layer*(NPAD*DMODEL);
    int n = rem >> 6, k = rem & 63;
    float v = (n < PROJ) ? Win[(size_t)layer*DMODEL*PROJ + k*PROJ + n] : 0.f;
    split2(v, g_WinTh[idx], g_WinTl[idx]);
  } else {
    int i2 = idx - NW;
    if (i2 < 8*DMODEL*DINNER) {
      int layer = i2 / (DMODEL*DINNER);
      int rem   = i2 - layer*(DMODEL*DINNER);
      int n = rem >> 7, k = rem & 127;
      float v = Wout[(size_t)layer*DINNER*DMODEL + k*DMODEL + n] * normw[layer*DINNER + k];
      split2(v, g_WoutTh[i2], g_WoutTl[i2]);
    }
  }
}

// ---- K18 (fused inproj + chunkA), per (b,h,ch) block ----
// R18 = R17 minus its LDS-conflict and WAR-barrier stalls:
//  - G-MFMA operands swapped: mfma(B,C) computes G^T tiles (bit-identical: fp mul
//    commutes, k-order unchanged). Lane then owns 4 consecutive s at fixed t ->
//    Gsh written with 4 packed 8B stores (~2-way) instead of 16 scalar 4-way ones.
//  - Gsh un-aliased (Bsh/Csh -> [64][36]); WAR barrier removed -> 3 barriers.
//    LDS total 40,672 B -> still 4 blocks/CU.
__global__ __launch_bounds__(256,4) void k_fusedAB(const float* __restrict__ xext, int sel,
                                                   const unsigned short* __restrict__ WinTh,
                                                   const unsigned short* __restrict__ WinTl,
                                                   const float* __restrict__ Win,
                                                   const float* __restrict__ dt_bias,
                                                   const float* __restrict__ A_log,
                                                   const float* __restrict__ conv_w,
                                                   const float* __restrict__ conv_b,
                                                   const float* __restrict__ Dp) {
  __shared__ struct {
    unsigned short Xt [64][72];        // X^T bf16 (9216 B)
    unsigned short Bt [32][72];        // (ew*B)^T bf16 (4608 B)
    float Hl[2][5][3][68];             // pre-conv halo rows (8160 B)
    unsigned short Bsh[64][36];        // 4608 B
    unsigned short Csh[64][36];        // 4608 B
    unsigned short Gsh[64][72];        // 9216 B (own buffer, no alias)
    float dtraw[64];                   // 256 B
  } S_;                                // 40,672 B total

  const float* __restrict__ X = (sel==0) ? xext : (sel==1 ? g_ping0 : g_ping1);
  const int bx = blockIdx.x; const int b = bx>>7, h = (bx>>6)&1, ch = bx&63;
  const int tid = threadIdx.x;
  const int w = tid>>6, l = tid&63, lane15 = l&15, quad = l>>4;
  const size_t row0 = (size_t)b*SEQ + (size_t)ch*QC;
  const int cbase = (b*NHEADS+h)*SEQ + ch*QC;
  const float dph = Dp[h];

  // ---- main A fragments (rows row0+16w+lane15), in-register split ----
  const float* xrow = &X[(row0 + 16*w + lane15)*DMODEL + quad*8];
  float4 f0 = *(const float4*)(xrow);
  float4 f1 = *(const float4*)(xrow + 4);
  float4 f2 = *(const float4*)(xrow + 32);
  float4 f3 = *(const float4*)(xrow + 36);
  short8 a0h, a0l, a1h, a1l;
  float v0[8] = {f0.x,f0.y,f0.z,f0.w,f1.x,f1.y,f1.z,f1.w};
  float v1[8] = {f2.x,f2.y,f2.z,f2.w,f3.x,f3.y,f3.z,f3.w};
  {
    unsigned short hh, ll;
#pragma unroll
    for (int j=0;j<8;j++){ split2(v0[j], hh, ll); a0h[j]=(short)hh; a0l[j]=(short)ll; }
#pragma unroll
    for (int j=0;j<8;j++){ split2(v1[j], hh, ll); a1h[j]=(short)hh; a1l[j]=(short)ll; }
  }

  // ---- dt partial dot from fragment values (coalesced inputs, no scatter) ----
  {
    const float* wd = &Win[DINNER + CONVDIM + h];   // Win[k*PROJ + dtcol]
    float p = 0.f;
#pragma unroll
    for (int j=0;j<8;j++) p = fmaf(v0[j], wd[(quad*8+j)*PROJ], p);
#pragma unroll
    for (int j=0;j<8;j++) p = fmaf(v1[j], wd[(32+quad*8+j)*PROJ], p);
    p += __shfl_xor(p, 16);
    p += __shfl_xor(p, 32);
    if (quad == 0) S_.dtraw[16*w + lane15] = p;     // full dot for row 16w+lane15
  }

  // 6-MFMA split-precision tile (identical op order to R12/R15)
  auto MFMA6 = [&](short8 A0h, short8 A1h, short8 A0l, short8 A1l, int t)->f32x4 {
    const unsigned short* bph = &WinTh[(16*t + lane15)*64 + quad*8];
    const unsigned short* bpl = &WinTl[(16*t + lane15)*64 + quad*8];
    short8 b0h = *(const short8*)bph;
    short8 b1h = *(const short8*)(bph + 32);
    short8 b0l = *(const short8*)bpl;
    short8 b1l = *(const short8*)(bpl + 32);
    f32x4 acc = {0.f,0.f,0.f,0.f};
    acc = __builtin_amdgcn_mfma_f32_16x16x32_bf16(A0h, b0h, acc, 0, 0, 0);
    acc = __builtin_amdgcn_mfma_f32_16x16x32_bf16(A1h, b1h, acc, 0, 0, 0);
    acc = __builtin_amdgcn_mfma_f32_16x16x32_bf16(A0l, b0h, acc, 0, 0, 0);
    acc = __builtin_amdgcn_mfma_f32_16x16x32_bf16(A1l, b1h, acc, 0, 0, 0);
    acc = __builtin_amdgcn_mfma_f32_16x16x32_bf16(A0h, b0l, acc, 0, 0, 0);
    acc = __builtin_amdgcn_mfma_f32_16x16x32_bf16(A1h, b1l, acc, 0, 0, 0);
    return acc;
  };

  // ---- halo tiles (shared scheme: wave w computes prev-chunk tile-col w) ----
  if (ch != 0){
    const float* xh = &X[(row0 - 16 + lane15)*DMODEL + quad*8];
    float4 g0 = *(const float4*)(xh);
    float4 g1 = *(const float4*)(xh + 4);
    float4 g2 = *(const float4*)(xh + 32);
    float4 g3 = *(const float4*)(xh + 36);
    short8 e0h, e0l, e1h, e1l;
    {
      float u0[8] = {g0.x,g0.y,g0.z,g0.w,g1.x,g1.y,g1.z,g1.w};
      float u1[8] = {g2.x,g2.y,g2.z,g2.w,g3.x,g3.y,g3.z,g3.w};
      unsigned short hh, ll;
#pragma unroll
      for (int j=0;j<8;j++){ split2(u0[j], hh, ll); e0h[j]=(short)hh; e0l[j]=(short)ll; }
#pragma unroll
      for (int j=0;j<8;j++){ split2(u1[j], hh, ll); e1h[j]=(short)hh; e1l[j]=(short)ll; }
    }
    f32x4 hA = MFMA6(e0h, e1h, e0l, e1l, 8+4*h+w);   // x-half halo tile (cols 16w..)
    f32x4 hB = MFMA6(e0h, e1h, e0l, e1l, 16+w);      // B/C halo tile
    if (quad == 3){
#pragma unroll
      for (int r=1;r<4;r++){
        S_.Hl[0][4][r-1][w*16+lane15] = hA[r];       // prev rows 61..63
        S_.Hl[1][4][r-1][w*16+lane15] = hB[r];
      }
    }
  } else if (tid < 192) {
    int j = tid>>6, n = tid&63;
    S_.Hl[0][4][j][n] = 0.f;
    S_.Hl[1][4][j][n] = 0.f;
  }

  // ---- z tiles: direct stores from MFMA layout (no staging, no barrier) ----
  {
#pragma unroll
    for (int tt=0; tt<4; tt++){
      f32x4 az = MFMA6(a0h, a1h, a0l, a1l, 4*h+tt);
#pragma unroll
      for (int r=0;r<4;r++)
        g_z[(row0 + 16*w + quad*4 + r)*DINNER + h*64 + tt*16 + lane15] = az[r];
    }
  }

  // ---- main pass tiles; quad3 rows 13..15 -> Hl for the next wave ----
  f32x4 pa[4];
#pragma unroll
  for (int tt=0; tt<4; tt++) pa[tt] = MFMA6(a0h, a1h, a0l, a1l, 8+4*h+tt);
  if (quad == 3){
#pragma unroll
    for (int tt=0; tt<4; tt++)
#pragma unroll
      for (int r=1;r<4;r++)
        S_.Hl[0][w][r-1][tt*16+lane15] = pa[tt][r];
  }
  f32x4 pb[4];
#pragma unroll
  for (int tt=0; tt<4; tt++) pb[tt] = MFMA6(a0h, a1h, a0l, a1l, 16+tt);
  if (quad == 3){
#pragma unroll
    for (int tt=0; tt<4; tt++)
#pragma unroll
      for (int r=1;r<4;r++)
        S_.Hl[1][w][r-1][tt*16+lane15] = pb[tt][r];
  }
  __syncthreads();   // barrier 1: Hl, dtraw visible

  // ---- dt scan, register-resident in every wave (identical chain) ----
  float cum, dtv, ewl;
  {
    float dr = S_.dtraw[l];
    float xv = dr + dt_bias[h];
    dtv = (xv > 20.f) ? xv : log1pf(expf(xv));
    float A = -expf(A_log[h]);
    cum = dtv * A;
#pragma unroll
    for (int off=1; off<64; off<<=1){
      float v = __shfl_up(cum, off);
      if (l >= off) cum += v;
    }
    if (w == 0){
      g_cum[cbase+l] = cum;
      if (l == 63) g_ctot[(b*NHEADS+h)*NCHUNK + ch] = cum;
    }
    float cl = __shfl(cum, 63);
    ewl = expf(cl - cum) * dtv;
  }

  const int t0 = 16*w + quad*4;

  // ---- conv + silu for x channels (in-register; quad0 halo from Hl) ----
  float sv[4][4];    // silu(x) at (t0+r, 16tt+lane15) — feeds Xt AND the Y-fold
#pragma unroll
  for (int tt=0; tt<4; tt++){
    const int n = tt*16 + lane15;
    const int gch = h*64 + n;
    const float w0 = conv_w[gch*4+0], w1 = conv_w[gch*4+1], w2 = conv_w[gch*4+2], w3 = conv_w[gch*4+3];
    const float bb = conv_b[gch];
    float o0 = pa[tt][0], o1 = pa[tt][1], o2 = pa[tt][2], o3 = pa[tt][3];
    float p1 = __shfl_up(o3, 16), p2 = __shfl_up(o2, 16), p3 = __shfl_up(o1, 16);
    if (quad == 0){
      const int slot = (w==0) ? 4 : (w-1);
      p1 = S_.Hl[0][slot][2][n];
      p2 = S_.Hl[0][slot][1][n];
      p3 = S_.Hl[0][slot][0][n];
    }
    float c0 = fmaf(w0,p3, fmaf(w1,p2, fmaf(w2,p1, fmaf(w3,o0, bb))));
    float c1 = fmaf(w0,p2, fmaf(w1,p1, fmaf(w2,o0, fmaf(w3,o1, bb))));
    float c2 = fmaf(w0,p1, fmaf(w1,o0, fmaf(w2,o1, fmaf(w3,o2, bb))));
    float c3 = fmaf(w0,o0, fmaf(w1,o1, fmaf(w2,o2, fmaf(w3,o3, bb))));
    sv[tt][0] = c0 / (1.f + expf(-c0));
    sv[tt][1] = c1 / (1.f + expf(-c1));
    sv[tt][2] = c2 / (1.f + expf(-c2));
    sv[tt][3] = c3 / (1.f + expf(-c3));
    ushort4v xq = { f2b(sv[tt][0]), f2b(sv[tt][1]), f2b(sv[tt][2]), f2b(sv[tt][3]) };
    *(ushort4v*)&S_.Xt[n][t0] = xq;
  }

  // ---- conv + silu for B/C channels (in-register; ew via shfl) ----
  {
    float ew0 = __shfl(ewl, t0+0), ew1 = __shfl(ewl, t0+1);
    float ew2 = __shfl(ewl, t0+2), ew3 = __shfl(ewl, t0+3);
#pragma unroll
    for (int tt=0; tt<4; tt++){
      const int nf = tt*16 + lane15;                 // 0..63 over B(0..31)|C(32..63)
      const int gch = 128 + nf;
      const float w0 = conv_w[gch*4+0], w1 = conv_w[gch*4+1], w2 = conv_w[gch*4+2], w3 = conv_w[gch*4+3];
      const float bb = conv_b[gch];
      float o0 = pb[tt][0], o1 = pb[tt][1], o2 = pb[tt][2], o3 = pb[tt][3];
      float p1 = __shfl_up(o3, 16), p2 = __shfl_up(o2, 16), p3 = __shfl_up(o1, 16);
      if (quad == 0){
        const int slot = (w==0) ? 4 : (w-1);
        p1 = S_.Hl[1][slot][2][nf];
        p2 = S_.Hl[1][slot][1][nf];
        p3 = S_.Hl[1][slot][0][nf];
      }
      float c0 = fmaf(w0,p3, fmaf(w1,p2, fmaf(w2,p1, fmaf(w3,o0, bb))));
      float c1 = fmaf(w0,p2, fmaf(w1,p1, fmaf(w2,o0, fmaf(w3,o1, bb))));
      float c2 = fmaf(w0,p1, fmaf(w1,o0, fmaf(w2,o1, fmaf(w3,o2, bb))));
      float c3 = fmaf(w0,o0, fmaf(w1,o1, fmaf(w2,o2, fmaf(w3,o3, bb))));
      float s0 = c0 / (1.f + expf(-c0));
      float s1 = c1 / (1.f + expf(-c1));
      float s2 = c2 / (1.f + expf(-c2));
      float s3 = c3 / (1.f + expf(-c3));
      if (tt < 2){                                   // B channels n = nf
        const int n = nf;
        S_.Bsh[t0+0][n] = f2b(s0);
        S_.Bsh[t0+1][n] = f2b(s1);
        S_.Bsh[t0+2][n] = f2b(s2);
        S_.Bsh[t0+3][n] = f2b(s3);
        ushort4v bq = { f2b(s0*ew0), f2b(s1*ew1), f2b(s2*ew2), f2b(s3*ew3) };
        *(ushort4v*)&S_.Bt[n][t0] = bq;
      } else {                                       // C channels n = nf-32
        const int n = nf - 32;
        S_.Csh[t0+0][n] = f2b(s0);
        S_.Csh[t0+1][n] = f2b(s1);
        S_.Csh[t0+2][n] = f2b(s2);
        S_.Csh[t0+3][n] = f2b(s3);
        if (h == 0){
          g_C[(row0+t0+0)*DSTATE + n] = f2b(s0);
          g_C[(row0+t0+1)*DSTATE + n] = f2b(s1);
          g_C[(row0+t0+2)*DSTATE + n] = f2b(s2);
          g_C[(row0+t0+3)*DSTATE + n] = f2b(s3);
        }
      }
    }
  }
  __syncthreads();   // barrier 2: Xt/Bsh/Csh/Bt visible

  // ---- SSD gate: G^T tiles via swapped MFMA (bit-identical products/sums) ----
  // A-operand = Bsh rows s-block w; B-operand = Csh rows t-block tb.
  // Lane owns s = 16w+quad4+r (4 consecutive), t = 16tb+lane15 (fixed).
  {
    short8 bfr = *(const short8*)&S_.Bsh[16*w + lane15][quad*8];
    f32x4 gaccT[4];
#pragma unroll
    for (int tb=0;tb<4;tb++){
      short8 cfr = *(const short8*)&S_.Csh[16*tb + lane15][quad*8];
      f32x4 z = {0.f,0.f,0.f,0.f};
      gaccT[tb] = __builtin_amdgcn_mfma_f32_16x16x32_bf16(bfr, cfr, z, 0, 0, 0);
    }
    float cs0 = __shfl(cum, t0+0), ds0 = __shfl(dtv, t0+0);
    float cs1 = __shfl(cum, t0+1), ds1 = __shfl(dtv, t0+1);
    float cs2 = __shfl(cum, t0+2), ds2 = __shfl(dtv, t0+2);
    float cs3 = __shfl(cum, t0+3), ds3 = __shfl(dtv, t0+3);
#pragma unroll
    for (int tb=0;tb<4;tb++){
      const int t = 16*tb + lane15;
      float ct = __shfl(cum, t);
      float g0 = (t0+0 <= t) ? expf(ct-cs0)*ds0*gaccT[tb][0] : 0.f;
      float g1 = (t0+1 <= t) ? expf(ct-cs1)*ds1*gaccT[tb][1] : 0.f;
      float g2 = (t0+2 <= t) ? expf(ct-cs2)*ds2*gaccT[tb][2] : 0.f;
      float g3 = (t0+3 <= t) ? expf(ct-cs3)*ds3*gaccT[tb][3] : 0.f;
      ushort4v gq = { f2b(g0), f2b(g1), f2b(g2), f2b(g3) };
      *(ushort4v*)&S_.Gsh[t][t0] = gq;               // packed 8B, ~2-way banks
    }
  }
  __syncthreads();   // barrier 3: Gsh visible

  // ---- Y = G·X + D*x ----
#pragma unroll
  for (int tn=0;tn<4;tn++){
    f32x4 acc = {0.f,0.f,0.f,0.f};
#pragma unroll
    for (int ks=0;ks<2;ks++){
      short8 a  = *(const short8*)&S_.Gsh[16*w  + lane15][quad*8 + 32*ks];
      short8 bf = *(const short8*)&S_.Xt [16*tn + lane15][quad*8 + 32*ks];
      acc = __builtin_amdgcn_mfma_f32_16x16x32_bf16(a, bf, acc, 0, 0, 0);
    }
    int p = 16*tn + lane15;
#pragma unroll
    for (int r=0;r<4;r++){
      int t = 16*w + quad*4 + r;
      g_y[(row0+t)*DINNER + h*HEADDIM + p] = acc[r] + dph * sv[tn][r];  // exact fp32 fold
    }
  }
  // ---- S = (ew B)^T·X ----
  const size_t sb = (size_t)((b*NHEADS+h)*NCHUNK + ch) * (DSTATE*HEADDIM);
  const int tm2 = w & 1, tnb = (w>>1)*2;
#pragma unroll
  for (int tt=0;tt<2;tt++){
    int tn2 = tnb + tt;
    f32x4 acc = {0.f,0.f,0.f,0.f};
#pragma unroll
    for (int ks=0;ks<2;ks++){
      short8 a  = *(const short8*)&S_.Bt[16*tm2 + lane15][quad*8 + 32*ks];
      short8 bf = *(const short8*)&S_.Xt[16*tn2 + lane15][quad*8 + 32*ks];
      acc = __builtin_amdgcn_mfma_f32_16x16x32_bf16(a, bf, acc, 0, 0, 0);
    }
    int p = 16*tn2 + lane15;
#pragma unroll
    for (int r=0;r<4;r++){
      int n = 16*tm2 + quad*4 + r;
      g_S[sb + n*HEADDIM + p] = acc[r];
    }
  }
}

// ---- K5: sequential-over-chunks state scan (software-pipelined, bit-identical chain) ----
__global__ __launch_bounds__(256) void k_chunkScan() {
  __shared__ float dAc[NCHUNK];            // exp(ctot) per chunk (uniform per block)
  const int idx = blockIdx.x*256 + threadIdx.x;
  const int np = idx & 2047;
  const int bh = idx >> 11;                // uniform within a 256-thread block
  if (threadIdx.x < NCHUNK) dAc[threadIdx.x] = expf(g_ctot[bh*NCHUNK + threadIdx.x]);
  __syncthreads();
  float h = 0.f;
  const size_t base = (size_t)bh*NCHUNK*2048 + np;
#pragma unroll 1
  for (int k0=0; k0<NCHUNK; k0+=8){
    float s[8];
#pragma unroll
    for (int j=0;j<8;j++) s[j] = g_S[base + (size_t)(k0+j)*2048];   // 8 independent loads
    float hs[8];
#pragma unroll
    for (int j=0;j<8;j++){
      hs[j] = h;                                                     // state at chunk start
      h = h*dAc[k0+j] + s[j];                                        // same chain order
    }
#pragma unroll
    for (int j=0;j<8;j++) g_H[base + (size_t)(k0+j)*2048] = hs[j];
  }
}

// ---- K6 (fused): inter-chunk y + gate + RMSNorm + split-MFMA out_proj ----
// Epilogue: per-wave LDS transpose (reusing yAh) -> 4KB contiguous row stores.
__global__ __launch_bounds__(256,3) void k_fusedC(const unsigned short* __restrict__ WoutTh,
                                                  const unsigned short* __restrict__ WoutTl,
                                                  float* __restrict__ dout, int dsel) {
  __shared__ float Cl[QC][DSTATE+1];             // 8.4 KB
  __shared__ float ec[NHEADS][QC];
  __shared__ unsigned short yAh[64][136];        // 17.4 KB (reused as store staging)
  __shared__ unsigned short yAl[64][136];        // 17.4 KB
  float* __restrict__ out = (dsel==0) ? g_ping0 : (dsel==1 ? g_ping1 : dout);
  const int bx = blockIdx.x; const int b = bx>>6, ch = bx&63;
  const int tid = threadIdx.x;
  const size_t row0 = (size_t)b*SEQ + (size_t)ch*QC;
  const int w = tid>>6, l = tid&63, lane15 = l&15, quad = l>>4;
#pragma unroll
  for (int j=0;j<8;j++){ int e=tid+j*256; int s=e>>5, n=e&31;
    Cl[s][n] = b2f(g_C[(row0+s)*DSTATE + n]); }
  if (tid < 128){ int h_=tid>>6, s=tid&63;
    ec[h_][s] = expf(g_cum[(b*NHEADS+h_)*SEQ + ch*QC + s]); }
  float hr[64];
  {
    const float* H0 = &g_H[(size_t)((b*NHEADS+0)*NCHUNK + ch)*2048];
    const float* H1 = &g_H[(size_t)((b*NHEADS+1)*NCHUNK + ch)*2048];
#pragma unroll
    for (int n=0;n<32;n++){ hr[n] = H0[n*64 + l]; hr[32+n] = H1[n*64 + l]; }
  }
  __syncthreads();
#pragma unroll 2
  for (int i=0;i<16;i++){
    const int r = 16*w + i;
    const size_t row = row0 + r;
    float d0 = 0.f, d1 = 0.f;
#pragma unroll
    for (int n=0;n<32;n++){
      float c = Cl[r][n];
      d0 = fmaf(c, hr[n],    d0);
      d1 = fmaf(c, hr[32+n], d1);
    }
    float yv0 = g_y[row*DINNER + l]      + ec[0][r]*d0;
    float yv1 = g_y[row*DINNER + l + 64] + ec[1][r]*d1;
    float z0 = g_z[row*DINNER + l];
    float z1 = g_z[row*DINNER + l + 64];
    yv0 *= z0 / (1.f + expf(-z0));
    yv1 *= z1 / (1.f + expf(-z1));
    float ss = yv0*yv0 + yv1*yv1;
#pragma unroll
    for (int off=32; off>=1; off>>=1) ss += __shfl_xor(ss, off);
    float sc = rsqrtf(ss*(1.f/128.f) + 1e-5f);
    split2(yv0*sc, yAh[r][l],    yAl[r][l]);
    split2(yv1*sc, yAh[r][l+64], yAl[r][l+64]);
  }
  __syncthreads();
  short8 afh[4], afl[4];
#pragma unroll
  for (int ks=0;ks<4;ks++){
    afh[ks] = *(const short8*)&yAh[16*w + lane15][quad*8 + 32*ks];
    afl[ks] = *(const short8*)&yAl[16*w + lane15][quad*8 + 32*ks];
  }
  __syncthreads();   // all yAh reads done; reuse as per-wave staging
  float (*stgF)[68] = (float(*)[68])((float*)&yAh[0][0] + (size_t)w*16*68);
#pragma unroll
  for (int tc=0;tc<4;tc++){
    f32x4 acc = {0.f,0.f,0.f,0.f};
#pragma unroll
    for (int ks=0;ks<4;ks++){
      const unsigned short* bph = &WoutTh[(16*tc + lane15)*DINNER + quad*8 + 32*ks];
      const unsigned short* bpl = &WoutTl[(16*tc + lane15)*DINNER + quad*8 + 32*ks];
      short8 bh  = *(const short8*)bph;
      short8 blo = *(const short8*)bpl;
      acc = __builtin_amdgcn_mfma_f32_16x16x32_bf16(afh[ks], bh,  acc, 0, 0, 0);
      acc = __builtin_amdgcn_mfma_f32_16x16x32_bf16(afl[ks], bh,  acc, 0, 0, 0);
      acc = __builtin_amdgcn_mfma_f32_16x16x32_bf16(afh[ks], blo, acc, 0, 0, 0);
    }
#pragma unroll
    for (int r=0;r<4;r++)
      stgF[quad*4+r][tc*16+lane15] = acc[r];
  }
#pragma unroll
  for (int it=0; it<4; it++){
    int e = it*64 + l;
    int lr = e>>4, c4 = (e&15)<<2;
    float4 v = *(const float4*)&stgF[lr][c4];
    *(float4*)&out[(row0 + 16*w + lr)*DMODEL + c4] = v;
  }
}

extern "C" void kernel_launch(void* const* d_in, const int* in_sizes, int n_in,
                              void* d_out, int out_size, void* d_ws, size_t ws_size,
                              hipStream_t stream) {
  (void)in_sizes; (void)n_in; (void)d_ws; (void)ws_size; (void)out_size;
  const float* x       = (const float*)d_in[0];
  const float* Win     = (const float*)d_in[1];
  const float* conv_w  = (const float*)d_in[2];
  const float* conv_b  = (const float*)d_in[3];
  const float* dt_bias = (const float*)d_in[4];
  const float* A_log   = (const float*)d_in[5];
  const float* Dp      = (const float*)d_in[6];
  const float* norm_w  = (const float*)d_in[7];
  const float* Wout    = (const float*)d_in[8];

  k_prep<<<(8*(NPAD*DMODEL + DMODEL*DINNER) + 255)/256, 256, 0, stream>>>(Win, Wout, norm_w);

  unsigned short *winTh, *winTl, *woutTh, *woutTl;
  hipGetSymbolAddress((void**)&winTh,  HIP_SYMBOL(g_WinTh));
  hipGetSymbolAddress((void**)&winTl,  HIP_SYMBOL(g_WinTl));
  hipGetSymbolAddress((void**)&woutTh, HIP_SYMBOL(g_WoutTh));
  hipGetSymbolAddress((void**)&woutTl, HIP_SYMBOL(g_WoutTl));

  for (int layer = 0; layer < 8; ++layer) {
    const int insel = (layer==0) ? 0 : ((((layer-1)&1)==0) ? 1 : 2);
    const int dsel  = (layer==7) ? 2 : ((layer&1)==0 ? 0 : 1);

    k_fusedAB<<<BATCH*NHEADS*NCHUNK, 256, 0, stream>>>(x, insel,
                                        winTh + (size_t)layer*NPAD*DMODEL,
                                        winTl + (size_t)layer*NPAD*DMODEL,
                                        Win + (size_t)layer*DMODEL*PROJ,
                                        dt_bias + layer*NHEADS, A_log + layer*NHEADS,
                                        conv_w + (size_t)layer*CONVDIM*4,
                                        conv_b + (size_t)layer*CONVDIM,
                                        Dp + layer*NHEADS);
    k_chunkScan<<<(BATCH*NHEADS*DSTATE*HEADDIM)/256, 256, 0, stream>>>();
    k_fusedC<<<BATCH*NCHUNK, 256, 0, stream>>>(woutTh + (size_t)layer*DMODEL*DINNER,
                                               woutTl + (size_t)layer*DMODEL*DINNER,
                                               (float*)d_out, dsel);
  }
}